// Round 1
// baseline (242.913 us; speedup 1.0000x reference)
//
#include <hip/hip_runtime.h>

// Linear attention, all-fp32 VALU version (no MFMA, no bf16 hi/lo split).
// Per bh: KV[d][c] = sum_s ke[s][d]*ve[s][c]/S ; ksum[d] = sum_s ke[s][d]
//         out[l][c] = S * (sum_d qe[l][d]*KV[d][c]) / (sum_d qe[l][d]*ksum[d] + 1e-6)
// Math per phase ~1.07e9 FMA = 13.7 us at fp32-VALU peak < 21 us memory floor
// (134 MB @ 6.3 TB/s) => fp32 outer-product reaches the memory roofline with
// ~3x less transform VALU than the split2/MFMA path, zero LDS transposes, and
// full fp32 accuracy.

#define S_LEN 8192
#define NBH 32
#define KVSTRIDE 4160   // 4096 KV entries + 64 ksum, per (bh, chunk)

typedef __attribute__((ext_vector_type(4))) float f32x4;

__device__ __forceinline__ float elu1(float x) {
  return x > 0.0f ? (x + 1.0f) : __expf(x);
}

// ---------------- Phase 1: partial KV + ksum over a segment of S ----------------
// Thread tile: 4(d) x 4(c). LDS stride 64: ke reads hit distinct bank-quads per
// dg, ve reads are 2-way (free). Register double-buffered staging (T14).
__global__ __launch_bounds__(256) void k1_partial(
    const float* __restrict__ kin, const float* __restrict__ vin,
    const int* __restrict__ kv_mask, float* __restrict__ partials, int seg_rows) {
  __shared__ float ke_lds[64 * 64];
  __shared__ float ve_lds[64 * 64];
  const int tid = threadIdx.x;
  const int seg = blockIdx.x, bh = blockIdx.y, b = bh >> 3;   // H=8
  const int rbase = seg * seg_rows;
  const int dg = tid >> 4, cg = tid & 15;
  const float* kbase = kin + (size_t)bh * S_LEN * 64;
  const float* vbase = vin + (size_t)bh * S_LEN * 64;
  const int* mbase = kv_mask + b * S_LEN;

  f32x4 ka[4], va[4], kb[4], vb[4];
  float ma[4], mb[4];
  float acc[4][4];
#pragma unroll
  for (int i = 0; i < 4; ++i)
#pragma unroll
    for (int j = 0; j < 4; ++j) acc[i][j] = 0.f;
  f32x4 ksump = {0.f, 0.f, 0.f, 0.f};

#define LOAD_T(K, V, M, r0_)                                           \
  {                                                                    \
    const float* kp_ = kbase + (size_t)(r0_) * 64;                     \
    const float* vp_ = vbase + (size_t)(r0_) * 64;                     \
    _Pragma("unroll")                                                  \
    for (int i_ = 0; i_ < 4; ++i_) {                                   \
      int f_ = tid + 256 * i_;                                         \
      K[i_] = *(const f32x4*)(kp_ + (size_t)f_ * 4);                   \
      V[i_] = *(const f32x4*)(vp_ + (size_t)f_ * 4);                   \
      M[i_] = mbase[(r0_) + (tid >> 4) + 16 * i_] ? 1.0f : 0.0f;       \
    }                                                                  \
  }

#define STORE_T(K, V, M)                                               \
  {                                                                    \
    _Pragma("unroll")                                                  \
    for (int i_ = 0; i_ < 4; ++i_) {                                   \
      int row_ = (tid >> 4) + 16 * i_;                                 \
      int c4_ = (tid & 15) * 4;                                        \
      float m_ = M[i_];                                                \
      float mv_ = m_ * (1.0f / 8192.0f);                               \
      f32x4 ke4_, ve4_;                                                \
      _Pragma("unroll")                                                \
      for (int j_ = 0; j_ < 4; ++j_) {                                 \
        ke4_[j_] = elu1(K[i_][j_]) * m_;                               \
        ve4_[j_] = V[i_][j_] * mv_;                                    \
      }                                                                \
      ksump += ke4_;     /* per-thread ksum partial over its 4 cols */ \
      *(f32x4*)&ke_lds[row_ * 64 + c4_] = ke4_;                        \
      *(f32x4*)&ve_lds[row_ * 64 + c4_] = ve4_;                        \
    }                                                                  \
  }

#define COMPUTE_T()                                                    \
  {                                                                    \
    _Pragma("unroll 4")                                                \
    for (int s_ = 0; s_ < 64; ++s_) {                                  \
      f32x4 kd_ = *(const f32x4*)&ke_lds[s_ * 64 + dg * 4];            \
      f32x4 vc_ = *(const f32x4*)&ve_lds[s_ * 64 + cg * 4];            \
      _Pragma("unroll")                                                \
      for (int i_ = 0; i_ < 4; ++i_)                                   \
        _Pragma("unroll")                                              \
        for (int j_ = 0; j_ < 4; ++j_)                                 \
          acc[i_][j_] = fmaf(kd_[i_], vc_[j_], acc[i_][j_]);           \
    }                                                                  \
  }

  const int ntiles = seg_rows >> 6;   // always even (seg_rows = 8192/nchunk >= 128)
  LOAD_T(ka, va, ma, rbase)
  for (int t = 0; t < ntiles; t += 2) {
    if (t) __syncthreads();                 // prev compute done reading LDS
    STORE_T(ka, va, ma)
    LOAD_T(kb, vb, mb, rbase + (t + 1) * 64)
    __syncthreads();
    COMPUTE_T()
    __syncthreads();
    STORE_T(kb, vb, mb)
    if (t + 2 < ntiles) LOAD_T(ka, va, ma, rbase + (t + 2) * 64)
    __syncthreads();
    COMPUTE_T()
  }

  // store partial KV [d][c] fp32 (coalesced float4)
  float* p = partials + ((size_t)bh * gridDim.x + seg) * KVSTRIDE;
#pragma unroll
  for (int i = 0; i < 4; ++i) {
    f32x4 o;
#pragma unroll
    for (int j = 0; j < 4; ++j) o[j] = acc[i][j];
    *(f32x4*)&p[(dg * 4 + i) * 64 + cg * 4] = o;
  }
  // ksum: reduce per-thread column partials (thread t covers cols (t&15)*4..+4)
  __syncthreads();
  *(f32x4*)&ke_lds[tid * 4] = ksump;
  __syncthreads();
  if (tid < 64) {
    float s = 0.f;
#pragma unroll
    for (int g = 0; g < 16; ++g)
      s += ke_lds[(g * 16 + (tid >> 2)) * 4 + (tid & 3)];
    p[4096 + tid] = s;
  }
#undef LOAD_T
#undef STORE_T
#undef COMPUTE_T
}

// ---------------- Phase 2: reduce partials -> fp32 KV [d][c] + ksum ----------------
__global__ __launch_bounds__(256) void k2_reduce(
    const float* __restrict__ partials, float* __restrict__ kvg, int nchunk) {
  const int idx = blockIdx.x * 256 + threadIdx.x;
  if (idx >= NBH * KVSTRIDE) return;
  const int bh = idx / KVSTRIDE;
  const int e = idx - bh * KVSTRIDE;
  const float* p = partials + (size_t)bh * nchunk * KVSTRIDE + e;
  float s0 = 0.f, s1 = 0.f, s2 = 0.f, s3 = 0.f;
  int c = 0;
  for (; c + 4 <= nchunk; c += 4) {
    s0 += p[(size_t)(c + 0) * KVSTRIDE];
    s1 += p[(size_t)(c + 1) * KVSTRIDE];
    s2 += p[(size_t)(c + 2) * KVSTRIDE];
    s3 += p[(size_t)(c + 3) * KVSTRIDE];
  }
  for (; c < nchunk; ++c) s0 += p[(size_t)c * KVSTRIDE];
  kvg[idx] = (s0 + s1) + (s2 + s3);
}

// ---------------- Phase 3: out = S * (qe.KV) / (qe.ksum + 1e-6) ----------------
// Thread tile: 4(l) x 4(c). qe_lds stride 66 -> the 4-row float2 reads land on
// distinct bank groups; kv_lds stride 64 -> 2-way (free). den folded into the
// staging pass as per-thread partial dots + one small LDS reduction.
__global__ __launch_bounds__(256) void k3_out(
    const float* __restrict__ qin, const int* __restrict__ q_mask,
    const float* __restrict__ kvg, float* __restrict__ out) {
  __shared__ float qe_lds[64 * 66];
  __shared__ float kv_lds[64 * 64];
  __shared__ float den_lds[256 * 4];
  __shared__ float inv_lds[64];
  const int tid = threadIdx.x;
  const int rb = blockIdx.x, bh = blockIdx.y, b = bh >> 3;
  const int r0 = rb * 64;
  const int lg = tid >> 4, cg = tid & 15;
  const float* kvb = kvg + (size_t)bh * KVSTRIDE;
  const f32x4 ks4 = *(const f32x4*)(kvb + 4096 + cg * 4);
  const float* qb = qin + ((size_t)bh * S_LEN + r0) * 64;

  f32x4 denp;
#pragma unroll
  for (int i = 0; i < 4; ++i) {
    int f = tid + 256 * i;
    int row = (tid >> 4) + 16 * i, c4 = cg * 4;
    float m = q_mask[b * S_LEN + r0 + row] ? 1.0f : 0.0f;
    f32x4 qw = *(const f32x4*)(qb + (size_t)f * 4);
    f32x4 qe;
#pragma unroll
    for (int j = 0; j < 4; ++j) qe[j] = elu1(qw[j]) * m;
    *(f32x4*)&qe_lds[row * 66 + c4] = qe;
    denp[i] = qe[0] * ks4[0] + qe[1] * ks4[1] + qe[2] * ks4[2] + qe[3] * ks4[3];
    *(f32x4*)&kv_lds[f * 4] = *(const f32x4*)(kvb + (size_t)f * 4);
  }
  *(f32x4*)&den_lds[tid * 4] = denp;
  __syncthreads();
  if (tid < 64) {
    // row r contributions live at threads (r&15)*16+g, slot r>>4
    float s = 0.f;
#pragma unroll
    for (int g = 0; g < 16; ++g)
      s += den_lds[((tid & 15) * 16 + g) * 4 + (tid >> 4)];
    inv_lds[tid] = 8192.0f / (s + 1e-6f);
  }

  float acc[4][4];
#pragma unroll
  for (int i = 0; i < 4; ++i)
#pragma unroll
    for (int j = 0; j < 4; ++j) acc[i][j] = 0.f;

#pragma unroll 8
  for (int d = 0; d < 64; d += 2) {
    float2 qv0 = *(const float2*)&qe_lds[(lg * 4 + 0) * 66 + d];
    float2 qv1 = *(const float2*)&qe_lds[(lg * 4 + 1) * 66 + d];
    float2 qv2 = *(const float2*)&qe_lds[(lg * 4 + 2) * 66 + d];
    float2 qv3 = *(const float2*)&qe_lds[(lg * 4 + 3) * 66 + d];
    f32x4 kv0 = *(const f32x4*)&kv_lds[d * 64 + cg * 4];
    f32x4 kv1 = *(const f32x4*)&kv_lds[(d + 1) * 64 + cg * 4];
#pragma unroll
    for (int j = 0; j < 4; ++j) {
      acc[0][j] = fmaf(qv0.x, kv0[j], fmaf(qv0.y, kv1[j], acc[0][j]));
      acc[1][j] = fmaf(qv1.x, kv0[j], fmaf(qv1.y, kv1[j], acc[1][j]));
      acc[2][j] = fmaf(qv2.x, kv0[j], fmaf(qv2.y, kv1[j], acc[2][j]));
      acc[3][j] = fmaf(qv3.x, kv0[j], fmaf(qv3.y, kv1[j], acc[3][j]));
    }
  }
  __syncthreads();   // inv_lds ready
#pragma unroll
  for (int il = 0; il < 4; ++il) {
    int row = lg * 4 + il;
    float inv = inv_lds[row];
    f32x4 o;
#pragma unroll
    for (int j = 0; j < 4; ++j) o[j] = acc[il][j] * inv;
    *(f32x4*)(out + ((size_t)bh * S_LEN + r0 + row) * 64 + cg * 4) = o;
  }
}

extern "C" void kernel_launch(void* const* d_in, const int* in_sizes, int n_in,
                              void* d_out, int out_size, void* d_ws, size_t ws_size,
                              hipStream_t stream) {
  const float* q = (const float*)d_in[0];
  const float* k = (const float*)d_in[1];
  const float* v = (const float*)d_in[2];
  const int* qm = (const int*)d_in[3];
  const int* km = (const int*)d_in[4];
  float* out = (float*)d_out;

  int nchunk = 64;   // 2048 k1 blocks -> 8 queued/CU for latency hiding
  while (nchunk > 1) {
    size_t need = (size_t)NBH * nchunk * KVSTRIDE * 4 + (size_t)NBH * KVSTRIDE * 4;
    if (need <= ws_size) break;
    nchunk >>= 1;
  }
  float* partials = (float*)d_ws;                       // [NBH][nchunk][KVSTRIDE]
  float* kvg = partials + (size_t)NBH * nchunk * KVSTRIDE;  // [NBH][KVSTRIDE]
  int seg_rows = S_LEN / nchunk;

  k1_partial<<<dim3(nchunk, NBH), 256, 0, stream>>>(k, v, km, partials, seg_rows);
  int n_elem = NBH * KVSTRIDE;
  k2_reduce<<<dim3((n_elem + 255) / 256), 256, 0, stream>>>(partials, kvg, nchunk);
  k3_out<<<dim3(S_LEN / 64, NBH), 256, 0, stream>>>(q, qm, kvg, out);
}